// Round 1
// baseline (590.484 us; speedup 1.0000x reference)
//
#include <hip/hip_runtime.h>
#include <math.h>

#define NUM_LEVELS 16
#define LOG2_T 19
#define TABLE_SIZE (1u << LOG2_T)

struct Scalings { float s[NUM_LEVELS]; };

__global__ __launch_bounds__(256) void hashenc_kernel(
    const float* __restrict__ xyzt,
    const float2* __restrict__ table,
    float2* __restrict__ out,
    Scalings sc,
    int n_pts)
{
    int tid = blockIdx.x * 256 + threadIdx.x;
    int n = tid >> 4;
    int l = tid & 15;
    if (n >= n_pts) return;

    float4 p = *reinterpret_cast<const float4*>(xyzt + (size_t)n * 4);
    float s = sc.s[l];
    float sx = p.x * s, sy = p.y * s, sz = p.z * s, st = p.w * s;
    float fx = floorf(sx), fy = floorf(sy), fz = floorf(sz), ft = floorf(st);
    float ox = sx - fx, oy = sy - fy, oz = sz - fz, ot = st - ft;

    unsigned xf = (unsigned)fx, yf = (unsigned)fy, zf = (unsigned)fz, tf = (unsigned)ft;
    unsigned xc = (unsigned)ceilf(sx), yc = (unsigned)ceilf(sy),
             zc = (unsigned)ceilf(sz), tc2 = (unsigned)ceilf(st);

    const unsigned P1 = 2654435761u, P2 = 805459861u, P3 = 3674653429u;
    unsigned mx[2] = { xf,        xc        };
    unsigned my[2] = { yf * P1,   yc * P1   };
    unsigned mz[2] = { zf * P2,   zc * P2   };
    unsigned mt[2] = { tf * P3,   tc2 * P3  };
    float wx[2] = { 1.0f - ox, ox };
    float wy[2] = { 1.0f - oy, oy };
    float wz[2] = { 1.0f - oz, oz };
    float wt[2] = { 1.0f - ot, ot };

    unsigned base = (unsigned)l << LOG2_T;

    // Issue all 16 gathers first for MLP, then reduce.
    float2 f[16];
    #pragma unroll
    for (int c = 0; c < 16; ++c) {
        unsigned h = mx[c & 1] ^ my[(c >> 1) & 1] ^ mz[(c >> 2) & 1] ^ mt[(c >> 3) & 1];
        unsigned idx = (h & (TABLE_SIZE - 1u)) + base;
        f[c] = table[idx];
    }

    float acc0 = 0.0f, acc1 = 0.0f;
    #pragma unroll
    for (int c = 0; c < 16; ++c) {
        float w = wx[c & 1] * wy[(c >> 1) & 1] * wz[(c >> 2) & 1] * wt[(c >> 3) & 1];
        acc0 = fmaf(f[c].x, w, acc0);
        acc1 = fmaf(f[c].y, w, acc1);
    }

    // out element tid (float2) == floats n*32 + l*2 : exactly the reference layout
    out[tid] = make_float2(acc0, acc1);
}

extern "C" void kernel_launch(void* const* d_in, const int* in_sizes, int n_in,
                              void* d_out, int out_size, void* d_ws, size_t ws_size,
                              hipStream_t stream) {
    const float*  xyzt  = (const float*)d_in[0];
    const float2* table = (const float2*)d_in[1];
    float2*       out   = (float2*)d_out;
    int n_pts = in_sizes[0] / 4;

    // Mirror numpy's float64 computation of _SCALINGS exactly (glibc pow/exp/log
    // are correctly rounded, matching npy_pow on the same machine).
    Scalings sc;
    double growth = exp((log(256.0) - log(16.0)) / 15.0);
    for (int l = 0; l < NUM_LEVELS; ++l)
        sc.s[l] = (float)floor(16.0 * pow(growth, (double)l));

    int total = n_pts * NUM_LEVELS;
    int block = 256;
    int grid = (total + block - 1) / block;
    hashenc_kernel<<<grid, block, 0, stream>>>(xyzt, table, out, sc, n_pts);
}

// Round 2
// 446.847 us; speedup vs baseline: 1.3214x; 1.3214x over previous
//
#include <hip/hip_runtime.h>
#include <math.h>

#define NUM_LEVELS 16
#define LOG2_T 19
#define TABLE_SIZE (1u << LOG2_T)

struct Scalings { float s[NUM_LEVELS]; };

__global__ __launch_bounds__(256) void hashenc_kernel(
    const float4* __restrict__ xyzt,
    const float2* __restrict__ table,
    float4* __restrict__ out,
    Scalings sc,
    int n_pts)
{
    int n = blockIdx.x * 256 + threadIdx.x;
    if (n >= n_pts) return;

    float4 p = xyzt[n];

    const unsigned P1 = 2654435761u, P2 = 805459861u, P3 = 3674653429u;
    float2 res[NUM_LEVELS];

    #pragma unroll
    for (int l = 0; l < NUM_LEVELS; ++l) {
        float s = sc.s[l];
        float sx = p.x * s, sy = p.y * s, sz = p.z * s, st = p.w * s;
        float fx = floorf(sx), fy = floorf(sy), fz = floorf(sz), ft = floorf(st);
        float ox = sx - fx, oy = sy - fy, oz = sz - fz, ot = st - ft;

        unsigned mx[2] = { (unsigned)fx,              (unsigned)ceilf(sx)              };
        unsigned my[2] = { (unsigned)fy * P1,         (unsigned)ceilf(sy) * P1         };
        unsigned mz[2] = { (unsigned)fz * P2,         (unsigned)ceilf(sz) * P2         };
        unsigned mt[2] = { (unsigned)ft * P3,         (unsigned)ceilf(st) * P3         };
        float wx[2] = { 1.0f - ox, ox };
        float wy[2] = { 1.0f - oy, oy };
        float wz[2] = { 1.0f - oz, oz };
        float wt[2] = { 1.0f - ot, ot };

        unsigned base = (unsigned)l << LOG2_T;

        // Issue all 16 gathers first (MLP), then reduce.
        float2 f[16];
        #pragma unroll
        for (int c = 0; c < 16; ++c) {
            unsigned h = mx[c & 1] ^ my[(c >> 1) & 1] ^ mz[(c >> 2) & 1] ^ mt[(c >> 3) & 1];
            unsigned idx = (h & (TABLE_SIZE - 1u)) + base;
            f[c] = table[idx];
        }

        float a0 = 0.0f, a1 = 0.0f;
        #pragma unroll
        for (int c = 0; c < 16; ++c) {
            float w = wx[c & 1] * wy[(c >> 1) & 1] * wz[(c >> 2) & 1] * wt[(c >> 3) & 1];
            a0 = fmaf(f[c].x, w, a0);
            a1 = fmaf(f[c].y, w, a1);
        }
        res[l] = make_float2(a0, a1);
    }

    // Each thread owns 128 contiguous output bytes: floats [n*32, n*32+32).
    float4* o = out + (size_t)n * 8;
    #pragma unroll
    for (int i = 0; i < 8; ++i)
        o[i] = make_float4(res[2 * i].x, res[2 * i].y, res[2 * i + 1].x, res[2 * i + 1].y);
}

extern "C" void kernel_launch(void* const* d_in, const int* in_sizes, int n_in,
                              void* d_out, int out_size, void* d_ws, size_t ws_size,
                              hipStream_t stream) {
    const float4* xyzt  = (const float4*)d_in[0];
    const float2* table = (const float2*)d_in[1];
    float4*       out   = (float4*)d_out;
    int n_pts = in_sizes[0] / 4;

    // Mirror numpy's float64 computation of _SCALINGS exactly.
    Scalings sc;
    double growth = exp((log(256.0) - log(16.0)) / 15.0);
    for (int l = 0; l < NUM_LEVELS; ++l)
        sc.s[l] = (float)floor(16.0 * pow(growth, (double)l));

    int block = 256;
    int grid = (n_pts + block - 1) / block;
    hashenc_kernel<<<grid, block, 0, stream>>>(xyzt, table, out, sc, n_pts);
}

// Round 3
// 269.608 us; speedup vs baseline: 2.1902x; 1.6574x over previous
//
#include <hip/hip_runtime.h>
#include <math.h>

#define NUM_LEVELS 16
#define LOG2_T 19
#define TABLE_SIZE (1u << LOG2_T)

struct Scalings { float s[NUM_LEVELS]; };

__global__ __launch_bounds__(256) void hashenc_kernel(
    const float4* __restrict__ xyzt,
    const float2* __restrict__ table,
    float2* __restrict__ out,
    Scalings sc,
    int n_pts,
    int blocks_per_level)
{
    // Level is uniform per block. Blocks with the same (blockIdx % 8) land on
    // the same XCD (round-robin dispatch); we give XCD k level k in phase 0,
    // then level 15-k in phase 1 (dispatch is roughly in blockIdx order), so
    // each XCD's 4MB L2 holds one 4MB level slice at a time.
    int b = blockIdx.x;
    int xcd = b & 7;
    int j = b >> 3;
    int phase = (j >= blocks_per_level) ? 1 : 0;
    int chunk = j - phase * blocks_per_level;
    int level = phase ? (15 - xcd) : xcd;

    int n = chunk * 256 + (int)threadIdx.x;
    if (n >= n_pts) return;

    float4 p = xyzt[n];
    float s = sc.s[level];

    float sx = p.x * s, sy = p.y * s, sz = p.z * s, st = p.w * s;
    float fx = floorf(sx), fy = floorf(sy), fz = floorf(sz), ft = floorf(st);
    float ox = sx - fx, oy = sy - fy, oz = sz - fz, ot = st - ft;

    const unsigned P1 = 2654435761u, P2 = 805459861u, P3 = 3674653429u;
    unsigned mx[2] = { (unsigned)fx,      (unsigned)ceilf(sx)      };
    unsigned my[2] = { (unsigned)fy * P1, (unsigned)ceilf(sy) * P1 };
    unsigned mz[2] = { (unsigned)fz * P2, (unsigned)ceilf(sz) * P2 };
    unsigned mt[2] = { (unsigned)ft * P3, (unsigned)ceilf(st) * P3 };
    float wx[2] = { 1.0f - ox, ox };
    float wy[2] = { 1.0f - oy, oy };
    float wz[2] = { 1.0f - oz, oz };
    float wt[2] = { 1.0f - ot, ot };

    unsigned base = (unsigned)level << LOG2_T;

    // Issue all 16 gathers first (MLP), then reduce.
    float2 f[16];
    #pragma unroll
    for (int c = 0; c < 16; ++c) {
        unsigned h = mx[c & 1] ^ my[(c >> 1) & 1] ^ mz[(c >> 2) & 1] ^ mt[(c >> 3) & 1];
        unsigned idx = (h & (TABLE_SIZE - 1u)) + base;
        f[c] = table[idx];
    }

    float a0 = 0.0f, a1 = 0.0f;
    #pragma unroll
    for (int c = 0; c < 16; ++c) {
        float w = wx[c & 1] * wy[(c >> 1) & 1] * wz[(c >> 2) & 1] * wt[(c >> 3) & 1];
        a0 = fmaf(f[c].x, w, a0);
        a1 = fmaf(f[c].y, w, a1);
    }

    out[(size_t)n * NUM_LEVELS + level] = make_float2(a0, a1);
}

extern "C" void kernel_launch(void* const* d_in, const int* in_sizes, int n_in,
                              void* d_out, int out_size, void* d_ws, size_t ws_size,
                              hipStream_t stream) {
    const float4* xyzt  = (const float4*)d_in[0];
    const float2* table = (const float2*)d_in[1];
    float2*       out   = (float2*)d_out;
    int n_pts = in_sizes[0] / 4;

    // Mirror numpy's float64 computation of _SCALINGS exactly.
    Scalings sc;
    double growth = exp((log(256.0) - log(16.0)) / 15.0);
    for (int l = 0; l < NUM_LEVELS; ++l)
        sc.s[l] = (float)floor(16.0 * pow(growth, (double)l));

    int block = 256;
    int blocks_per_level = (n_pts + block - 1) / block;
    int grid = 2 * 8 * blocks_per_level;  // 2 phases x 8 XCD-levels
    hashenc_kernel<<<grid, block, 0, stream>>>(xyzt, table, out, sc, n_pts, blocks_per_level);
}

// Round 4
// 247.818 us; speedup vs baseline: 2.3827x; 1.0879x over previous
//
#include <hip/hip_runtime.h>
#include <math.h>

#define NUM_LEVELS 16
#define LOG2_T 19
#define TABLE_SIZE (1u << LOG2_T)

struct Scalings { float s[NUM_LEVELS]; };

__global__ __launch_bounds__(256) void hashenc_kernel(
    const float4* __restrict__ xyzt,
    const float2* __restrict__ table,
    float2* __restrict__ dst,     // scratch [L][N] if use_scratch, else out [N][L]
    Scalings sc,
    int n_pts,
    int blocks_per_level,
    int use_scratch)
{
    // b = level*bpl + chunk. With round-robin b%8 -> XCD dispatch, all XCDs
    // work on the SAME level concurrently (each on 1/8 of the points), so each
    // XCD's L2 holds a replica of the single hot 4MB level slice, and the
    // level mix per XCD is identical -> no inter-XCD load imbalance.
    unsigned b = blockIdx.x;
    unsigned level = b / (unsigned)blocks_per_level;
    unsigned chunk = b - level * (unsigned)blocks_per_level;

    int n = (int)(chunk * 256u + threadIdx.x);
    if (n >= n_pts || level >= NUM_LEVELS) return;

    float4 p = xyzt[n];
    float s = sc.s[level];

    float sx = p.x * s, sy = p.y * s, sz = p.z * s, st = p.w * s;
    float fx = floorf(sx), fy = floorf(sy), fz = floorf(sz), ft = floorf(st);
    float ox = sx - fx, oy = sy - fy, oz = sz - fz, ot = st - ft;

    const unsigned P1 = 2654435761u, P2 = 805459861u, P3 = 3674653429u;
    unsigned mx[2] = { (unsigned)fx,      (unsigned)ceilf(sx)      };
    unsigned my[2] = { (unsigned)fy * P1, (unsigned)ceilf(sy) * P1 };
    unsigned mz[2] = { (unsigned)fz * P2, (unsigned)ceilf(sz) * P2 };
    unsigned mt[2] = { (unsigned)ft * P3, (unsigned)ceilf(st) * P3 };
    float wx[2] = { 1.0f - ox, ox };
    float wy[2] = { 1.0f - oy, oy };
    float wz[2] = { 1.0f - oz, oz };
    float wt[2] = { 1.0f - ot, ot };

    unsigned base = level << LOG2_T;

    // Issue all 16 gathers first (MLP), then reduce.
    float2 f[16];
    #pragma unroll
    for (int c = 0; c < 16; ++c) {
        unsigned h = mx[c & 1] ^ my[(c >> 1) & 1] ^ mz[(c >> 2) & 1] ^ mt[(c >> 3) & 1];
        unsigned idx = (h & (TABLE_SIZE - 1u)) + base;
        f[c] = table[idx];
    }

    float a0 = 0.0f, a1 = 0.0f;
    #pragma unroll
    for (int c = 0; c < 16; ++c) {
        float w = wx[c & 1] * wy[(c >> 1) & 1] * wz[(c >> 2) & 1] * wt[(c >> 3) & 1];
        a0 = fmaf(f[c].x, w, a0);
        a1 = fmaf(f[c].y, w, a1);
    }

    if (use_scratch)
        dst[(size_t)level * n_pts + n] = make_float2(a0, a1);  // coalesced, no RMW
    else
        dst[(size_t)n * NUM_LEVELS + level] = make_float2(a0, a1);
}

__global__ __launch_bounds__(256) void transpose_kernel(
    const float2* __restrict__ ws,
    float4* __restrict__ out,
    int n_pts)
{
    int n = blockIdx.x * 256 + (int)threadIdx.x;
    if (n >= n_pts) return;
    float2 v[NUM_LEVELS];
    #pragma unroll
    for (int l = 0; l < NUM_LEVELS; ++l)
        v[l] = ws[(size_t)l * n_pts + n];        // 512B/wave coalesced per level
    float4* o = out + (size_t)n * 8;
    #pragma unroll
    for (int i = 0; i < 8; ++i)                  // 128B/thread contiguous
        o[i] = make_float4(v[2 * i].x, v[2 * i].y, v[2 * i + 1].x, v[2 * i + 1].y);
}

extern "C" void kernel_launch(void* const* d_in, const int* in_sizes, int n_in,
                              void* d_out, int out_size, void* d_ws, size_t ws_size,
                              hipStream_t stream) {
    const float4* xyzt  = (const float4*)d_in[0];
    const float2* table = (const float2*)d_in[1];
    int n_pts = in_sizes[0] / 4;

    // Mirror numpy's float64 computation of _SCALINGS exactly.
    Scalings sc;
    double growth = exp((log(256.0) - log(16.0)) / 15.0);
    for (int l = 0; l < NUM_LEVELS; ++l)
        sc.s[l] = (float)floor(16.0 * pow(growth, (double)l));

    int block = 256;
    int bpl = (n_pts + block - 1) / block;
    int grid = NUM_LEVELS * bpl;

    size_t need = (size_t)NUM_LEVELS * n_pts * sizeof(float2);
    int use_scratch = (d_ws != nullptr && ws_size >= need) ? 1 : 0;

    float2* dst = use_scratch ? (float2*)d_ws : (float2*)d_out;
    hashenc_kernel<<<grid, block, 0, stream>>>(xyzt, table, dst, sc, n_pts, bpl, use_scratch);

    if (use_scratch) {
        transpose_kernel<<<bpl, block, 0, stream>>>((const float2*)d_ws, (float4*)d_out, n_pts);
    }
}

// Round 5
// 216.868 us; speedup vs baseline: 2.7228x; 1.1427x over previous
//
#include <hip/hip_runtime.h>
#include <math.h>

#define NUM_LEVELS 16
#define LOG2_T 19
#define TABLE_SIZE (1u << LOG2_T)
#define MASK (TABLE_SIZE - 1u)

struct Scalings { float s[NUM_LEVELS]; };

__global__ __launch_bounds__(256) void hashenc_kernel(
    const float4* __restrict__ xyzt,
    const float2* __restrict__ table,
    float2* __restrict__ dst,     // scratch [L][N] if use_scratch, else out [N][L]
    Scalings sc,
    int n_pts,
    int blocks_per_level,
    int use_scratch)
{
    // b = level*bpl + chunk: all XCDs work the SAME level concurrently, each
    // XCD's L2 holds a replica of the one hot 4MB slice; identical level mix
    // per XCD -> no imbalance (round-3/4 finding).
    unsigned b = blockIdx.x;
    unsigned level = b / (unsigned)blocks_per_level;
    unsigned chunk = b - level * (unsigned)blocks_per_level;

    int n = (int)(chunk * 256u + threadIdx.x);
    if (n >= n_pts || level >= NUM_LEVELS) return;

    float4 p = xyzt[n];
    float s = sc.s[level];

    float sx = p.x * s, sy = p.y * s, sz = p.z * s, st = p.w * s;
    float fx = floorf(sx), fy = floorf(sy), fz = floorf(sz), ft = floorf(st);
    float ox = sx - fx, oy = sy - fy, oz = sz - fz, ot = st - ft;

    const unsigned P1 = 2654435761u, P2 = 805459861u, P3 = 3674653429u;
    unsigned xf = (unsigned)fx, xc = (unsigned)ceilf(sx);
    unsigned my_[2] = { (unsigned)fy * P1, (unsigned)ceilf(sy) * P1 };
    unsigned mz_[2] = { (unsigned)fz * P2, (unsigned)ceilf(sz) * P2 };
    unsigned mt_[2] = { (unsigned)ft * P3, (unsigned)ceilf(st) * P3 };
    float wx0 = 1.0f - ox, wx1 = ox;
    float wy_[2] = { 1.0f - oy, oy };
    float wz_[2] = { 1.0f - oz, oz };
    float wt_[2] = { 1.0f - ot, ot };

    unsigned rest[8]; float wrest[8];
    #pragma unroll
    for (int r = 0; r < 8; ++r) {
        rest[r]  = my_[r & 1] ^ mz_[(r >> 1) & 1] ^ mt_[(r >> 2) & 1];
        wrest[r] = wy_[r & 1] * wz_[(r >> 1) & 1] * wt_[(r >> 2) & 1];
    }

    unsigned base = level << LOG2_T;
    float a0 = 0.0f, a1 = 0.0f;

    // x-prime is 1: when xf is even and xc==xf+1, the two x-corners of each
    // pair differ only in hash bit 0 -> same 16B-aligned table block -> ONE
    // float4 gather fetches both corners (8 line-requests instead of 16).
    bool merge = ((xf & 1u) == 0u) && (xc == xf + 1u);
    if (merge) {
        const float4* t4 = (const float4*)table;
        #pragma unroll
        for (int r = 0; r < 8; ++r) {
            unsigned g = ((xf ^ rest[r]) & MASK) + base;   // index of x-bit-0 corner
            float4 v = t4[g >> 1];                          // covers {g&~1, g|1}
            bool hi = (g & 1u) != 0u;                       // which half is x-bit-0
            float c0x = hi ? v.z : v.x, c0y = hi ? v.w : v.y;
            float c1x = hi ? v.x : v.z, c1y = hi ? v.y : v.w;
            float wl = wrest[r];
            a0 = fmaf(wl, fmaf(wx0, c0x, wx1 * c1x), a0);
            a1 = fmaf(wl, fmaf(wx0, c0y, wx1 * c1y), a1);
        }
    } else {
        #pragma unroll
        for (int r = 0; r < 8; ++r) {
            unsigned g0 = ((xf ^ rest[r]) & MASK) + base;
            unsigned g1 = ((xc ^ rest[r]) & MASK) + base;
            float2 v0 = table[g0];
            float2 v1 = table[g1];
            float wl = wrest[r];
            a0 = fmaf(wl, fmaf(wx0, v0.x, wx1 * v1.x), a0);
            a1 = fmaf(wl, fmaf(wx0, v0.y, wx1 * v1.y), a1);
        }
    }

    if (use_scratch)
        dst[(size_t)level * n_pts + n] = make_float2(a0, a1);  // coalesced, no RMW
    else
        dst[(size_t)n * NUM_LEVELS + level] = make_float2(a0, a1);
}

// 2 points per thread: float4 reads from ws (halved request count), 256B
// contiguous writes per thread.
__global__ __launch_bounds__(256) void transpose2_kernel(
    const float4* __restrict__ ws4,   // [L][N/2] float4
    float4* __restrict__ out,
    int n2)
{
    int t = blockIdx.x * 256 + (int)threadIdx.x;
    if (t >= n2) return;
    float4 v[NUM_LEVELS];
    #pragma unroll
    for (int l = 0; l < NUM_LEVELS; ++l)
        v[l] = ws4[(size_t)l * n2 + t];          // points {2t,2t+1} at level l
    float4* o = out + (size_t)(2 * t) * 8;
    #pragma unroll
    for (int i = 0; i < 8; ++i)
        o[i] = make_float4(v[2 * i].x, v[2 * i].y, v[2 * i + 1].x, v[2 * i + 1].y);
    #pragma unroll
    for (int i = 0; i < 8; ++i)
        o[8 + i] = make_float4(v[2 * i].z, v[2 * i].w, v[2 * i + 1].z, v[2 * i + 1].w);
}

__global__ __launch_bounds__(256) void transpose_kernel(
    const float2* __restrict__ ws,
    float4* __restrict__ out,
    int n_pts)
{
    int n = blockIdx.x * 256 + (int)threadIdx.x;
    if (n >= n_pts) return;
    float2 v[NUM_LEVELS];
    #pragma unroll
    for (int l = 0; l < NUM_LEVELS; ++l)
        v[l] = ws[(size_t)l * n_pts + n];
    float4* o = out + (size_t)n * 8;
    #pragma unroll
    for (int i = 0; i < 8; ++i)
        o[i] = make_float4(v[2 * i].x, v[2 * i].y, v[2 * i + 1].x, v[2 * i + 1].y);
}

extern "C" void kernel_launch(void* const* d_in, const int* in_sizes, int n_in,
                              void* d_out, int out_size, void* d_ws, size_t ws_size,
                              hipStream_t stream) {
    const float4* xyzt  = (const float4*)d_in[0];
    const float2* table = (const float2*)d_in[1];
    int n_pts = in_sizes[0] / 4;

    // Mirror numpy's float64 computation of _SCALINGS exactly.
    Scalings sc;
    double growth = exp((log(256.0) - log(16.0)) / 15.0);
    for (int l = 0; l < NUM_LEVELS; ++l)
        sc.s[l] = (float)floor(16.0 * pow(growth, (double)l));

    int block = 256;
    int bpl = (n_pts + block - 1) / block;
    int grid = NUM_LEVELS * bpl;

    size_t need = (size_t)NUM_LEVELS * n_pts * sizeof(float2);
    int use_scratch = (d_ws != nullptr && ws_size >= need) ? 1 : 0;

    float2* dst = use_scratch ? (float2*)d_ws : (float2*)d_out;
    hashenc_kernel<<<grid, block, 0, stream>>>(xyzt, table, dst, sc, n_pts, bpl, use_scratch);

    if (use_scratch) {
        if ((n_pts & 1) == 0) {
            int n2 = n_pts / 2;
            int g2 = (n2 + block - 1) / block;
            transpose2_kernel<<<g2, block, 0, stream>>>((const float4*)d_ws, (float4*)d_out, n2);
        } else {
            transpose_kernel<<<bpl, block, 0, stream>>>((const float2*)d_ws, (float4*)d_out, n_pts);
        }
    }
}